// Round 25
// baseline (229.077 us; speedup 1.0000x reference)
//
#include <hip/hip_runtime.h>

#define NN 100000
#define NE 3200000
#define HD 20
#define EHD 64
#define EOUTD 10
#define TBINS 4096

// ---- radix/counting sort geometry ----
#define EPB 2048
#define NBLKS1 1563                // ceil(NE/EPB)
#define NBINS1 256                 // pass-1 bins: src>>9 in [0,196)
#define N1 (NBINS1 * NBLKS1)       // 400128
#define NBUCK 196
#define WIN 4096
#define WPB 6                      // windows per bucket
#define NWIN (NBUCK * WPB)         // 1176
#define N2 (NBUCK * 512 * WPB)     // 602112

// ---------------- generic scan: per-1024-block ----------------
__global__ void scan1_kernel(int* __restrict__ data, int* __restrict__ bsum, int n) {
    __shared__ int s[1024];
    int t = threadIdx.x;
    int i = blockIdx.x * 1024 + t;
    int v = (i < n) ? data[i] : 0;
    s[t] = v;
    __syncthreads();
    for (int off = 1; off < 1024; off <<= 1) {
        int add = (t >= off) ? s[t - off] : 0;
        __syncthreads();
        s[t] += add;
        __syncthreads();
    }
    if (i < n) data[i] = s[t] - v;            // exclusive, block-local
    if (t == 1023) bsum[blockIdx.x] = s[t];
}

__global__ void scan2_kernel(int* __restrict__ bsum, int nb) {
    __shared__ int s[1024];
    int t = threadIdx.x;
    int v = (t < nb) ? bsum[t] : 0;
    s[t] = v;
    __syncthreads();
    for (int off = 1; off < 1024; off <<= 1) {
        int add = (t >= off) ? s[t - off] : 0;
        __syncthreads();
        s[t] += add;
        __syncthreads();
    }
    if (t < nb) bsum[t] = s[t] - v;           // exclusive
}

__global__ void scan3_kernel(int* __restrict__ data, const int* __restrict__ bsum, int n) {
    int i = blockIdx.x * blockDim.x + threadIdx.x;
    if (i < n) data[i] += bsum[i >> 10];
}

// scan3 for M2 that also emits offsets (folds old offs_kernel)
__global__ void scan3b_kernel(int* __restrict__ data, const int* __restrict__ bsum,
                              int* __restrict__ offsets) {
    int i = blockIdx.x * blockDim.x + threadIdx.x;
    if (i >= N2) return;
    int v = data[i] + bsum[i >> 10];
    data[i] = v;
    if (i % WPB == 0) {
        int nb = i / WPB;                     // = bucket*512 + bin
        if (nb <= NN) offsets[nb] = v;        // nb==NN slot exists (196*512>NN)
    }
}

// ---------------- pass 1 histogram (bin = src>>9) ----------------
__global__ void hist1_kernel(const int* __restrict__ ei, int* __restrict__ counts1) {
    __shared__ int h[NBINS1];
    int t = threadIdx.x;
    h[t] = 0;
    __syncthreads();
    int base = blockIdx.x * EPB;
    for (int j = t; j < EPB; j += 256) {
        int e = base + j;
        if (e < NE) atomicAdd(&h[ei[e] >> 9], 1);
    }
    __syncthreads();
    counts1[t * NBLKS1 + blockIdx.x] = h[t];     // bin-major
}

// ---------------- pass 1 scatter (unstable, LDS cursors) ----------------
__global__ void scatter1_kernel(const int* __restrict__ ei,
                                const float* __restrict__ ea,
                                const int* __restrict__ counts1s,
                                unsigned short* __restrict__ key1,
                                int2* __restrict__ pk1) {
    __shared__ int cur[NBINS1];
    int t = threadIdx.x;
    cur[t] = counts1s[t * NBLKS1 + blockIdx.x];
    __syncthreads();
    int base = blockIdx.x * EPB;
    for (int j = t; j < EPB; j += 256) {
        int e = base + j;
        if (e >= NE) break;
        int src = ei[e];
        int pos = atomicAdd(&cur[src >> 9], 1);
        key1[pos] = (unsigned short)(src & 511);
        int2 pk;
        pk.x = ei[NE + e];
        pk.y = __float_as_int(ea[e]);
        pk1[pos] = pk;
    }
}

// ---------------- pass 2 histogram ----------------
__global__ void hist2_kernel(const unsigned short* __restrict__ key1,
                             const int* __restrict__ counts1s,
                             int* __restrict__ M2) {
    __shared__ int h[512];
    int t = threadIdx.x;
    h[t] = 0; h[t + 256] = 0;
    __syncthreads();
    int b = blockIdx.x / WPB, w = blockIdx.x % WPB;
    int bstart = counts1s[b * NBLKS1];
    int bend   = counts1s[(b + 1) * NBLKS1];
    int start = bstart + w * WIN;
    int end = (start + WIN < bend) ? (start + WIN) : bend;
    for (int i = start + t; i < end; i += 256) atomicAdd(&h[key1[i]], 1);
    __syncthreads();
    M2[((b * 512) + t) * WPB + w]       = h[t];
    M2[((b * 512) + t + 256) * WPB + w] = h[t + 256];
}

// ---------------- pass 2 scatter (final positions) ----------------
__global__ void scatter2_kernel(const unsigned short* __restrict__ key1,
                                const int2* __restrict__ pk1,
                                const int* __restrict__ counts1s,
                                const int* __restrict__ M2s,
                                int2* __restrict__ csr_pk) {
    __shared__ int cur[512];
    int t = threadIdx.x;
    int b = blockIdx.x / WPB, w = blockIdx.x % WPB;
    cur[t]       = M2s[((b * 512) + t) * WPB + w];
    cur[t + 256] = M2s[((b * 512) + t + 256) * WPB + w];
    __syncthreads();
    int bstart = counts1s[b * NBLKS1];
    int bend   = counts1s[(b + 1) * NBLKS1];
    int start = bstart + w * WIN;
    int end = (start + WIN < bend) ? (start + WIN) : bend;
    for (int i = start + t; i < end; i += 256) {
        int pos = atomicAdd(&cur[key1[i]], 1);
        csr_pk[pos] = pk1[i];
    }
}

// ---------------- MLP table: bf16 {val,delta} pairs, 64B rows ------------
__global__ void table_kernel(const float* __restrict__ W1,
                             const float* __restrict__ b1,
                             const float* __restrict__ W2,
                             const float* __restrict__ b2,
                             unsigned short* __restrict__ tab) {
    int i = blockIdx.x * blockDim.x + threadIdx.x;
    if (i >= TBINS) return;
    float m0[EOUTD], m1[EOUTD];
    float d0 = (float)i * (10.0f / (float)TBINS);
    float d1 = (float)(i + 1) * (10.0f / (float)TBINS);
    #pragma unroll
    for (int j = 0; j < EOUTD; ++j) { m0[j] = b2[j]; m1[j] = b2[j]; }
    for (int k = 0; k < EHD; ++k) {
        float h0 = fmaxf(fmaf(d0, W1[k], b1[k]), 0.0f);
        float h1 = fmaxf(fmaf(d1, W1[k], b1[k]), 0.0f);
        #pragma unroll
        for (int j = 0; j < EOUTD; ++j) {
            m0[j] = fmaf(h0, W2[k * EOUTD + j], m0[j]);
            m1[j] = fmaf(h1, W2[k * EOUTD + j], m1[j]);
        }
    }
    unsigned short* row = tab + (size_t)i * 32;
    #pragma unroll
    for (int j = 0; j < EOUTD; ++j) {
        unsigned int uv = __float_as_uint(m0[j]);
        unsigned int ud = __float_as_uint(m1[j] - m0[j]);
        uv = (uv + 0x7fffu + ((uv >> 16) & 1u)) >> 16;
        ud = (ud + 0x7fffu + ((ud >> 16) & 1u)) >> 16;
        row[2 * j]     = (unsigned short)uv;
        row[2 * j + 1] = (unsigned short)ud;
    }
    #pragma unroll
    for (int j = 20; j < 32; ++j) row[j] = 0;
}

// ---------------- pack x[:,0,:] as int pairs (bf16(x[k]), bf16(x[k+10])) --
// xbf2[node*16 + k] for k=0..9; 64B rows
__global__ void xpack2_kernel(const float* __restrict__ x,
                              int* __restrict__ xbf2) {
    int t = blockIdx.x * blockDim.x + threadIdx.x;
    if (t >= NN * 16) return;
    int node = t >> 4, k = t & 15;
    int v = 0;
    if (k < 10) {
        unsigned int u0 = __float_as_uint(x[(size_t)node * 2 * HD + k]);
        unsigned int u1 = __float_as_uint(x[(size_t)node * 2 * HD + k + 10]);
        u0 = (u0 + 0x7fffu + ((u0 >> 16) & 1u)) >> 16;   // RNE bf16
        u1 = (u1 + 0x7fffu + ((u1 >> 16) & 1u)) >> 16;
        v = (int)(u0 | (u1 << 16));
    }
    xbf2[t] = v;
}

// ---------------- node-owner kernel: 10 lanes/node, 2 features/lane -------
__launch_bounds__(256)
__global__ void node_kernel(const int* __restrict__ offsets,
                            const int2* __restrict__ csr_pk,
                            const float* __restrict__ x,
                            const int* __restrict__ xbf2,
                            const unsigned short* __restrict__ tab,
                            const float* __restrict__ pa,
                            const float* __restrict__ pb,
                            const float* __restrict__ g1,
                            const float* __restrict__ g2,
                            const float* __restrict__ bias,
                            float* __restrict__ out) {
    int tid  = threadIdx.x;
    int wave = tid >> 6;
    int lane = tid & 63;
    int sub  = lane / 10;                  // 0..5 active, 6 = idle lanes
    int fk   = lane - sub * 10;            // feature pair id 0..9
    int node = blockIdx.x * 24 + wave * 6 + sub;
    bool active = (sub < 6) && (node < NN);

    float a = pa[0], bb = pb[0];
    float oma = 1.0f - a;

    int off0 = 0, deg = 0;
    float xs_lo = 0.0f, xs_hi = 0.0f, axs_lo = 0.0f, axs_hi = 0.0f;
    if (active) {
        off0 = offsets[node];
        deg  = offsets[node + 1] - off0;
        xs_lo = x[(size_t)node * 2 * HD + fk];
        xs_hi = x[(size_t)node * 2 * HD + fk + 10];
        axs_lo = a * xs_lo;
        axs_hi = a * xs_hi;
    }

    float S0a = 0.0f, S1a = 0.0f, Sra = 0.0f;   // feature fk (one-hot)
    float S0b = 0.0f, S1b = 0.0f, Srb = 0.0f;   // feature fk+10 (table)

    auto process = [&](int dst, int db) {
        float d = __int_as_float(db);
        int idx = (int)d; if (idx > 9) idx = 9;
        float u = d * ((float)TBINS / 10.0f);
        int ti = (int)u; if (ti > TBINS - 1) ti = TBINS - 1;
        float fr = u - (float)ti;
        unsigned int xw = (unsigned int)xbf2[(((size_t)(unsigned int)dst) << 4) + fk];
        unsigned int tv = *(const unsigned int*)(tab + (((size_t)ti) << 5) + fk * 2);
        float xd_lo = __uint_as_float(xw << 16);
        float xd_hi = __uint_as_float(xw & 0xffff0000u);
        float t0 = fmaf(-oma, xd_lo, axs_lo);
        float t1 = fmaf(-oma, xd_hi, axs_hi);
        float r0 = (t0 != 0.0f)
            ? __builtin_amdgcn_exp2f(bb * __builtin_amdgcn_logf(fabsf(t0))) : 0.0f;
        float r1 = (t1 != 0.0f)
            ? __builtin_amdgcn_exp2f(bb * __builtin_amdgcn_logf(fabsf(t1))) : 0.0f;
        Sra += r0; Srb += r1;
        float c0 = (fk == idx) ? 1.0f : 0.0f;
        float val = __uint_as_float(tv << 16);
        float del = __uint_as_float(tv & 0xffff0000u);
        float c1 = fmaxf(fmaf(fr, del, val), 0.0f);
        S0a += c0; S1a = fmaf(r0, c0, S1a);
        S0b += c1; S1b = fmaf(r1, c1, S1b);
    };

    for (int base = 0; base < deg; base += 10) {
        int nchunk = deg - base; if (nchunk > 10) nchunk = 10;
        // clamped (branch-free) coalesced preload of this chunk's (dst,d)
        int idxc = off0 + base + ((fk < nchunk) ? fk : (nchunk - 1));
        int2 pk = csr_pk[idxc];
        int dstv = pk.x, dbits = pk.y;
        int jj = 0;
        for (; jj + 1 < nchunk; jj += 2) {
            int dA = __shfl(dstv, sub * 10 + jj, 64);
            int bA = __shfl(dbits, sub * 10 + jj, 64);
            int dB = __shfl(dstv, sub * 10 + jj + 1, 64);
            int bB = __shfl(dbits, sub * 10 + jj + 1, 64);
            process(dA, bA);
            process(dB, bB);
        }
        if (jj < nchunk) {
            int dA = __shfl(dstv, sub * 10 + jj, 64);
            int bA = __shfl(dbits, sub * 10 + jj, 64);
            process(dA, bA);
        }
    }

    float sf_lo = (S0a != 0.0f) ? (S1a / S0a) : (0.01f * Sra);
    float sf_hi = (S0b != 0.0f) ? (S1b / S0b) : (0.01f * Srb);

    if (active) {
        // epilogue: lane fk computes output rows fk and fk+10
        float acc0 = bias[fk];
        float acc1 = bias[fk + 10];
        const float* g1r0 = g1 + fk * HD;
        const float* g1r1 = g1 + (fk + 10) * HD;
        const float* g2r0 = g2 + fk * HD;
        const float* g2r1 = g2 + (fk + 10) * HD;
        #pragma unroll
        for (int j = 0; j < 10; ++j) {
            int sl = sub * 10 + j;
            float xj  = __shfl(xs_lo, sl, 64);
            float xj1 = __shfl(xs_hi, sl, 64);
            float sj  = __shfl(sf_lo, sl, 64);
            float sj1 = __shfl(sf_hi, sl, 64);
            acc0 = fmaf(xj, g1r0[j], acc0);  acc0 = fmaf(xj1, g1r0[j + 10], acc0);
            acc0 = fmaf(sj, g2r0[j], acc0);  acc0 = fmaf(sj1, g2r0[j + 10], acc0);
            acc1 = fmaf(xj, g1r1[j], acc1);  acc1 = fmaf(xj1, g1r1[j + 10], acc1);
            acc1 = fmaf(sj, g2r1[j], acc1);  acc1 = fmaf(sj1, g2r1[j + 10], acc1);
        }
        float* op = out + (size_t)node * 2 * HD;
        op[fk]          = fmaxf(acc0, 0.0f);
        op[fk + 10]     = fmaxf(acc1, 0.0f);
        op[HD + fk]     = sf_lo;
        op[HD + fk + 10] = sf_hi;
    }
}

extern "C" void kernel_launch(void* const* d_in, const int* in_sizes, int n_in,
                              void* d_out, int out_size, void* d_ws, size_t ws_size,
                              hipStream_t stream) {
    const float* x    = (const float*)d_in[0];
    const int*   ei   = (const int*)d_in[1];
    const float* ea   = (const float*)d_in[2];
    const float* pa   = (const float*)d_in[3];
    const float* pb   = (const float*)d_in[4];
    const float* g1   = (const float*)d_in[5];
    const float* g2   = (const float*)d_in[6];
    const float* bias = (const float*)d_in[7];
    const float* W1   = (const float*)d_in[8];
    const float* b1   = (const float*)d_in[9];
    const float* W2   = (const float*)d_in[10];
    const float* b2   = (const float*)d_in[11];
    float* out = (float*)d_out;

    // workspace layout (all segments 128B-aligned)
    char* ws = (char*)d_ws;
    int*   counts1 = (int*)ws;     ws += ((size_t)N1 * 4 + 127) / 128 * 128;
    int*   bsum1   = (int*)ws;     ws += (1024 * 4 + 127) / 128 * 128;
    int*   M2      = (int*)ws;     ws += ((size_t)N2 * 4 + 127) / 128 * 128;
    int*   bsum2   = (int*)ws;     ws += (1024 * 4 + 127) / 128 * 128;
    int*   offsets = (int*)ws;     ws += ((size_t)(NN + 1) * 4 + 127) / 128 * 128;
    unsigned short* key1 = (unsigned short*)ws;  ws += ((size_t)NE * 2 + 127) / 128 * 128;
    int2*  pk1     = (int2*)ws;    ws += (size_t)NE * 8;
    int2*  csr_pk  = (int2*)ws;    ws += (size_t)NE * 8;
    unsigned short* tab = (unsigned short*)ws;   ws += ((size_t)TBINS * 32 * 2 + 127) / 128 * 128;
    int*   xbf2    = (int*)ws;     ws += ((size_t)NN * 16 * 4 + 127) / 128 * 128;

    table_kernel<<<(TBINS + 255) / 256, 256, 0, stream>>>(W1, b1, W2, b2, tab);
    xpack2_kernel<<<(NN * 16 + 255) / 256, 256, 0, stream>>>(x, xbf2);

    // pass 1: group by bucket (src>>9)
    hist1_kernel<<<NBLKS1, 256, 0, stream>>>(ei, counts1);
    scan1_kernel<<<(N1 + 1023) / 1024, 1024, 0, stream>>>(counts1, bsum1, N1);
    scan2_kernel<<<1, 1024, 0, stream>>>(bsum1, (N1 + 1023) / 1024);
    scan3_kernel<<<(N1 + 255) / 256, 256, 0, stream>>>(counts1, bsum1, N1);
    scatter1_kernel<<<NBLKS1, 256, 0, stream>>>(ei, ea, counts1, key1, pk1);

    // pass 2: within bucket, bin = src & 511 (== exact node)
    hist2_kernel<<<NWIN, 256, 0, stream>>>(key1, counts1, M2);
    scan1_kernel<<<(N2 + 1023) / 1024, 1024, 0, stream>>>(M2, bsum2, N2);
    scan2_kernel<<<1, 1024, 0, stream>>>(bsum2, (N2 + 1023) / 1024);
    scan3b_kernel<<<(N2 + 255) / 256, 256, 0, stream>>>(M2, bsum2, offsets);
    scatter2_kernel<<<NWIN, 256, 0, stream>>>(key1, pk1, counts1, M2, csr_pk);

    node_kernel<<<(NN + 23) / 24, 256, 0, stream>>>(offsets, csr_pk, x, xbf2, tab,
                                                    pa, pb, g1, g2, bias, out);
}

// Round 26
// 198.502 us; speedup vs baseline: 1.1540x; 1.1540x over previous
//
#include <hip/hip_runtime.h>

#define NN 100000
#define NE 3200000
#define HD 20
#define EHD 64
#define EOUTD 10
#define TBINS 4096

// ---- radix/counting sort geometry ----
#define EPB 8192
#define NBLKS1 391                 // ceil(NE/EPB)
#define NBINS1 256                 // pass-1 bins: src>>9 in [0,196)
#define N1 (NBINS1 * NBLKS1)       // 100096
#define NBUCK 196
#define WIN 4096
#define WPB 6                      // windows per bucket
#define NWIN (NBUCK * WPB)         // 1176
#define N2 (NBUCK * 512 * WPB)     // 602112

// ---------------- generic scan: per-1024-block ----------------
__global__ void scan1_kernel(int* __restrict__ data, int* __restrict__ bsum, int n) {
    __shared__ int s[1024];
    int t = threadIdx.x;
    int i = blockIdx.x * 1024 + t;
    int v = (i < n) ? data[i] : 0;
    s[t] = v;
    __syncthreads();
    for (int off = 1; off < 1024; off <<= 1) {
        int add = (t >= off) ? s[t - off] : 0;
        __syncthreads();
        s[t] += add;
        __syncthreads();
    }
    if (i < n) data[i] = s[t] - v;            // exclusive, block-local
    if (t == 1023) bsum[blockIdx.x] = s[t];
}

__global__ void scan2_kernel(int* __restrict__ bsum, int nb) {
    __shared__ int s[1024];
    int t = threadIdx.x;
    int v = (t < nb) ? bsum[t] : 0;
    s[t] = v;
    __syncthreads();
    for (int off = 1; off < 1024; off <<= 1) {
        int add = (t >= off) ? s[t - off] : 0;
        __syncthreads();
        s[t] += add;
        __syncthreads();
    }
    if (t < nb) bsum[t] = s[t] - v;           // exclusive
}

__global__ void scan3_kernel(int* __restrict__ data, const int* __restrict__ bsum, int n) {
    int i = blockIdx.x * blockDim.x + threadIdx.x;
    if (i < n) data[i] += bsum[i >> 10];
}

// scan3 for M2 that also emits offsets (folds old offs_kernel)
__global__ void scan3b_kernel(int* __restrict__ data, const int* __restrict__ bsum,
                              int* __restrict__ offsets) {
    int i = blockIdx.x * blockDim.x + threadIdx.x;
    if (i >= N2) return;
    int v = data[i] + bsum[i >> 10];
    data[i] = v;
    if (i % WPB == 0) {
        int nb = i / WPB;                     // = bucket*512 + bin
        if (nb <= NN) offsets[nb] = v;        // nb==NN slot exists (196*512>NN)
    }
}

// ---------------- pass 1 histogram (bin = src>>9), 1024 threads ----------
__global__ void hist1_kernel(const int* __restrict__ ei, int* __restrict__ counts1) {
    __shared__ int h[NBINS1];
    int t = threadIdx.x;
    if (t < NBINS1) h[t] = 0;
    __syncthreads();
    int base = blockIdx.x * EPB;
    for (int j = t; j < EPB; j += 1024) {
        int e = base + j;
        if (e < NE) atomicAdd(&h[ei[e] >> 9], 1);
    }
    __syncthreads();
    if (t < NBINS1) counts1[t * NBLKS1 + blockIdx.x] = h[t];   // bin-major
}

// ---------------- pass 1 scatter (unstable, LDS cursors), 1024 threads ----
__global__ void scatter1_kernel(const int* __restrict__ ei,
                                const float* __restrict__ ea,
                                const int* __restrict__ counts1s,
                                unsigned short* __restrict__ key1,
                                int2* __restrict__ pk1) {
    __shared__ int cur[NBINS1];
    int t = threadIdx.x;
    if (t < NBINS1) cur[t] = counts1s[t * NBLKS1 + blockIdx.x];
    __syncthreads();
    int base = blockIdx.x * EPB;
    for (int j = t; j < EPB; j += 1024) {
        int e = base + j;
        if (e >= NE) break;
        int src = ei[e];
        int pos = atomicAdd(&cur[src >> 9], 1);
        key1[pos] = (unsigned short)(src & 511);
        int2 pk;
        pk.x = ei[NE + e];
        pk.y = __float_as_int(ea[e]);
        pk1[pos] = pk;
    }
}

// ---------------- pass 2 histogram ----------------
__global__ void hist2_kernel(const unsigned short* __restrict__ key1,
                             const int* __restrict__ counts1s,
                             int* __restrict__ M2) {
    __shared__ int h[512];
    int t = threadIdx.x;
    h[t] = 0; h[t + 256] = 0;
    __syncthreads();
    int b = blockIdx.x / WPB, w = blockIdx.x % WPB;
    int bstart = counts1s[b * NBLKS1];
    int bend   = counts1s[(b + 1) * NBLKS1];
    int start = bstart + w * WIN;
    int end = (start + WIN < bend) ? (start + WIN) : bend;
    for (int i = start + t; i < end; i += 256) atomicAdd(&h[key1[i]], 1);
    __syncthreads();
    M2[((b * 512) + t) * WPB + w]       = h[t];
    M2[((b * 512) + t + 256) * WPB + w] = h[t + 256];
}

// ---------------- pass 2 scatter (final positions) ----------------
__global__ void scatter2_kernel(const unsigned short* __restrict__ key1,
                                const int2* __restrict__ pk1,
                                const int* __restrict__ counts1s,
                                const int* __restrict__ M2s,
                                int2* __restrict__ csr_pk) {
    __shared__ int cur[512];
    int t = threadIdx.x;
    int b = blockIdx.x / WPB, w = blockIdx.x % WPB;
    cur[t]       = M2s[((b * 512) + t) * WPB + w];
    cur[t + 256] = M2s[((b * 512) + t + 256) * WPB + w];
    __syncthreads();
    int bstart = counts1s[b * NBLKS1];
    int bend   = counts1s[(b + 1) * NBLKS1];
    int start = bstart + w * WIN;
    int end = (start + WIN < bend) ? (start + WIN) : bend;
    for (int i = start + t; i < end; i += 256) {
        int pos = atomicAdd(&cur[key1[i]], 1);
        csr_pk[pos] = pk1[i];
    }
}

// ---------------- MLP table: bf16 {val,delta} pairs, 64B rows ------------
__global__ void table_kernel(const float* __restrict__ W1,
                             const float* __restrict__ b1,
                             const float* __restrict__ W2,
                             const float* __restrict__ b2,
                             unsigned short* __restrict__ tab) {
    int i = blockIdx.x * blockDim.x + threadIdx.x;
    if (i >= TBINS) return;
    float m0[EOUTD], m1[EOUTD];
    float d0 = (float)i * (10.0f / (float)TBINS);
    float d1 = (float)(i + 1) * (10.0f / (float)TBINS);
    #pragma unroll
    for (int j = 0; j < EOUTD; ++j) { m0[j] = b2[j]; m1[j] = b2[j]; }
    for (int k = 0; k < EHD; ++k) {
        float h0 = fmaxf(fmaf(d0, W1[k], b1[k]), 0.0f);
        float h1 = fmaxf(fmaf(d1, W1[k], b1[k]), 0.0f);
        #pragma unroll
        for (int j = 0; j < EOUTD; ++j) {
            m0[j] = fmaf(h0, W2[k * EOUTD + j], m0[j]);
            m1[j] = fmaf(h1, W2[k * EOUTD + j], m1[j]);
        }
    }
    unsigned short* row = tab + (size_t)i * 32;
    #pragma unroll
    for (int j = 0; j < EOUTD; ++j) {
        unsigned int uv = __float_as_uint(m0[j]);
        unsigned int ud = __float_as_uint(m1[j] - m0[j]);
        uv = (uv + 0x7fffu + ((uv >> 16) & 1u)) >> 16;
        ud = (ud + 0x7fffu + ((ud >> 16) & 1u)) >> 16;
        row[2 * j]     = (unsigned short)uv;
        row[2 * j + 1] = (unsigned short)ud;
    }
    #pragma unroll
    for (int j = 20; j < 32; ++j) row[j] = 0;
}

// ---------------- pack x[:,0,:] as int pairs (bf16(x[k]), bf16(x[k+10])) --
// xbf2[node*16 + k] for k=0..9; 64B rows
__global__ void xpack2_kernel(const float* __restrict__ x,
                              int* __restrict__ xbf2) {
    int t = blockIdx.x * blockDim.x + threadIdx.x;
    if (t >= NN * 16) return;
    int node = t >> 4, k = t & 15;
    int v = 0;
    if (k < 10) {
        unsigned int u0 = __float_as_uint(x[(size_t)node * 2 * HD + k]);
        unsigned int u1 = __float_as_uint(x[(size_t)node * 2 * HD + k + 10]);
        u0 = (u0 + 0x7fffu + ((u0 >> 16) & 1u)) >> 16;   // RNE bf16
        u1 = (u1 + 0x7fffu + ((u1 >> 16) & 1u)) >> 16;
        v = (int)(u0 | (u1 << 16));
    }
    xbf2[t] = v;
}

// ---------------- node-owner kernel: 10 lanes/node, 2 features/lane -------
__launch_bounds__(256)
__global__ void node_kernel(const int* __restrict__ offsets,
                            const int2* __restrict__ csr_pk,
                            const float* __restrict__ x,
                            const int* __restrict__ xbf2,
                            const unsigned short* __restrict__ tab,
                            const float* __restrict__ pa,
                            const float* __restrict__ pb,
                            const float* __restrict__ g1,
                            const float* __restrict__ g2,
                            const float* __restrict__ bias,
                            float* __restrict__ out) {
    int tid  = threadIdx.x;
    int wave = tid >> 6;
    int lane = tid & 63;
    int sub  = lane / 10;                  // 0..5 active, 6 = idle lanes
    int fk   = lane - sub * 10;            // feature pair id 0..9
    int node = blockIdx.x * 24 + wave * 6 + sub;
    bool active = (sub < 6) && (node < NN);

    float a = pa[0], bb = pb[0];
    float oma = 1.0f - a;

    int off0 = 0, deg = 0;
    float xs_lo = 0.0f, xs_hi = 0.0f, axs_lo = 0.0f, axs_hi = 0.0f;
    if (active) {
        off0 = offsets[node];
        deg  = offsets[node + 1] - off0;
        xs_lo = x[(size_t)node * 2 * HD + fk];
        xs_hi = x[(size_t)node * 2 * HD + fk + 10];
        axs_lo = a * xs_lo;
        axs_hi = a * xs_hi;
    }

    float S0a = 0.0f, S1a = 0.0f, Sra = 0.0f;   // feature fk (one-hot)
    float S0b = 0.0f, S1b = 0.0f, Srb = 0.0f;   // feature fk+10 (table)

    auto process = [&](int dst, int db) {
        float d = __int_as_float(db);
        int idx = (int)d; if (idx > 9) idx = 9;
        float u = d * ((float)TBINS / 10.0f);
        int ti = (int)u; if (ti > TBINS - 1) ti = TBINS - 1;
        float fr = u - (float)ti;
        unsigned int xw = (unsigned int)xbf2[(((size_t)(unsigned int)dst) << 4) + fk];
        unsigned int tv = *(const unsigned int*)(tab + (((size_t)ti) << 5) + fk * 2);
        float xd_lo = __uint_as_float(xw << 16);
        float xd_hi = __uint_as_float(xw & 0xffff0000u);
        float t0 = fmaf(-oma, xd_lo, axs_lo);
        float t1 = fmaf(-oma, xd_hi, axs_hi);
        float r0 = (t0 != 0.0f)
            ? __builtin_amdgcn_exp2f(bb * __builtin_amdgcn_logf(fabsf(t0))) : 0.0f;
        float r1 = (t1 != 0.0f)
            ? __builtin_amdgcn_exp2f(bb * __builtin_amdgcn_logf(fabsf(t1))) : 0.0f;
        Sra += r0; Srb += r1;
        float c0 = (fk == idx) ? 1.0f : 0.0f;
        float val = __uint_as_float(tv << 16);
        float del = __uint_as_float(tv & 0xffff0000u);
        float c1 = fmaxf(fmaf(fr, del, val), 0.0f);
        S0a += c0; S1a = fmaf(r0, c0, S1a);
        S0b += c1; S1b = fmaf(r1, c1, S1b);
    };

    for (int base = 0; base < deg; base += 10) {
        int nchunk = deg - base; if (nchunk > 10) nchunk = 10;
        // clamped (branch-free) coalesced preload of this chunk's (dst,d)
        int idxc = off0 + base + ((fk < nchunk) ? fk : (nchunk - 1));
        int2 pk = csr_pk[idxc];
        int dstv = pk.x, dbits = pk.y;
        int jj = 0;
        for (; jj + 1 < nchunk; jj += 2) {
            int dA = __shfl(dstv, sub * 10 + jj, 64);
            int bA = __shfl(dbits, sub * 10 + jj, 64);
            int dB = __shfl(dstv, sub * 10 + jj + 1, 64);
            int bB = __shfl(dbits, sub * 10 + jj + 1, 64);
            process(dA, bA);
            process(dB, bB);
        }
        if (jj < nchunk) {
            int dA = __shfl(dstv, sub * 10 + jj, 64);
            int bA = __shfl(dbits, sub * 10 + jj, 64);
            process(dA, bA);
        }
    }

    float sf_lo = (S0a != 0.0f) ? (S1a / S0a) : (0.01f * Sra);
    float sf_hi = (S0b != 0.0f) ? (S1b / S0b) : (0.01f * Srb);

    if (active) {
        // epilogue: lane fk computes output rows fk and fk+10
        float acc0 = bias[fk];
        float acc1 = bias[fk + 10];
        const float* g1r0 = g1 + fk * HD;
        const float* g1r1 = g1 + (fk + 10) * HD;
        const float* g2r0 = g2 + fk * HD;
        const float* g2r1 = g2 + (fk + 10) * HD;
        #pragma unroll
        for (int j = 0; j < 10; ++j) {
            int sl = sub * 10 + j;
            float xj  = __shfl(xs_lo, sl, 64);
            float xj1 = __shfl(xs_hi, sl, 64);
            float sj  = __shfl(sf_lo, sl, 64);
            float sj1 = __shfl(sf_hi, sl, 64);
            acc0 = fmaf(xj, g1r0[j], acc0);  acc0 = fmaf(xj1, g1r0[j + 10], acc0);
            acc0 = fmaf(sj, g2r0[j], acc0);  acc0 = fmaf(sj1, g2r0[j + 10], acc0);
            acc1 = fmaf(xj, g1r1[j], acc1);  acc1 = fmaf(xj1, g1r1[j + 10], acc1);
            acc1 = fmaf(sj, g2r1[j], acc1);  acc1 = fmaf(sj1, g2r1[j + 10], acc1);
        }
        float* op = out + (size_t)node * 2 * HD;
        op[fk]          = fmaxf(acc0, 0.0f);
        op[fk + 10]     = fmaxf(acc1, 0.0f);
        op[HD + fk]     = sf_lo;
        op[HD + fk + 10] = sf_hi;
    }
}

extern "C" void kernel_launch(void* const* d_in, const int* in_sizes, int n_in,
                              void* d_out, int out_size, void* d_ws, size_t ws_size,
                              hipStream_t stream) {
    const float* x    = (const float*)d_in[0];
    const int*   ei   = (const int*)d_in[1];
    const float* ea   = (const float*)d_in[2];
    const float* pa   = (const float*)d_in[3];
    const float* pb   = (const float*)d_in[4];
    const float* g1   = (const float*)d_in[5];
    const float* g2   = (const float*)d_in[6];
    const float* bias = (const float*)d_in[7];
    const float* W1   = (const float*)d_in[8];
    const float* b1   = (const float*)d_in[9];
    const float* W2   = (const float*)d_in[10];
    const float* b2   = (const float*)d_in[11];
    float* out = (float*)d_out;

    // workspace layout (all segments 128B-aligned)
    char* ws = (char*)d_ws;
    int*   counts1 = (int*)ws;     ws += ((size_t)N1 * 4 + 127) / 128 * 128;
    int*   bsum1   = (int*)ws;     ws += (1024 * 4 + 127) / 128 * 128;
    int*   M2      = (int*)ws;     ws += ((size_t)N2 * 4 + 127) / 128 * 128;
    int*   bsum2   = (int*)ws;     ws += (1024 * 4 + 127) / 128 * 128;
    int*   offsets = (int*)ws;     ws += ((size_t)(NN + 1) * 4 + 127) / 128 * 128;
    unsigned short* key1 = (unsigned short*)ws;  ws += ((size_t)NE * 2 + 127) / 128 * 128;
    int2*  pk1     = (int2*)ws;    ws += (size_t)NE * 8;
    int2*  csr_pk  = (int2*)ws;    ws += (size_t)NE * 8;
    unsigned short* tab = (unsigned short*)ws;   ws += ((size_t)TBINS * 32 * 2 + 127) / 128 * 128;
    int*   xbf2    = (int*)ws;     ws += ((size_t)NN * 16 * 4 + 127) / 128 * 128;

    table_kernel<<<(TBINS + 255) / 256, 256, 0, stream>>>(W1, b1, W2, b2, tab);
    xpack2_kernel<<<(NN * 16 + 255) / 256, 256, 0, stream>>>(x, xbf2);

    // pass 1: group by bucket (src>>9)
    hist1_kernel<<<NBLKS1, 1024, 0, stream>>>(ei, counts1);
    scan1_kernel<<<(N1 + 1023) / 1024, 1024, 0, stream>>>(counts1, bsum1, N1);
    scan2_kernel<<<1, 1024, 0, stream>>>(bsum1, (N1 + 1023) / 1024);
    scan3_kernel<<<(N1 + 255) / 256, 256, 0, stream>>>(counts1, bsum1, N1);
    scatter1_kernel<<<NBLKS1, 1024, 0, stream>>>(ei, ea, counts1, key1, pk1);

    // pass 2: within bucket, bin = src & 511 (== exact node)
    hist2_kernel<<<NWIN, 256, 0, stream>>>(key1, counts1, M2);
    scan1_kernel<<<(N2 + 1023) / 1024, 1024, 0, stream>>>(M2, bsum2, N2);
    scan2_kernel<<<1, 1024, 0, stream>>>(bsum2, (N2 + 1023) / 1024);
    scan3b_kernel<<<(N2 + 255) / 256, 256, 0, stream>>>(M2, bsum2, offsets);
    scatter2_kernel<<<NWIN, 256, 0, stream>>>(key1, pk1, counts1, M2, csr_pk);

    node_kernel<<<(NN + 23) / 24, 256, 0, stream>>>(offsets, csr_pk, x, xbf2, tab,
                                                    pa, pb, g1, g2, bias, out);
}

// Round 27
// 174.623 us; speedup vs baseline: 1.3118x; 1.1368x over previous
//
#include <hip/hip_runtime.h>

#define NN 100000
#define NE 3200000
#define HD 20
#define EHD 64
#define EOUTD 10
#define TBINS 4096

// ---- radix/counting sort geometry ----
#define EPB 8192
#define NBLKS1 391                 // ceil(NE/EPB)
#define NBINS1 256                 // pass-1 bins: src>>9 in [0,196)
#define N1 (NBINS1 * NBLKS1)       // 100096
#define NBUCK 196
#define WIN 4096
#define WPB 6                      // windows per bucket
#define NWIN (NBUCK * WPB)         // 1176
#define N2 (NBUCK * 512 * WPB)     // 602112
#define KMASK 0x1FFFF              // low 17 bits = dst

// ---------------- scan1: per-1024-block exclusive + block sums ----------
__global__ void scan1_kernel(int* __restrict__ data, int* __restrict__ bsum, int n) {
    __shared__ int s[1024];
    int t = threadIdx.x;
    int i = blockIdx.x * 1024 + t;
    int v = (i < n) ? data[i] : 0;
    s[t] = v;
    __syncthreads();
    for (int off = 1; off < 1024; off <<= 1) {
        int add = (t >= off) ? s[t - off] : 0;
        __syncthreads();
        s[t] += add;
        __syncthreads();
    }
    if (i < n) data[i] = s[t] - v;            // exclusive, block-local
    if (t == 1023) bsum[blockIdx.x] = s[t];
}

// ---------------- scan3f: LDS-scan raw block sums, then add base ---------
__global__ void scan3f_kernel(int* __restrict__ data, const int* __restrict__ bsum,
                              int nb, int n) {
    __shared__ int s[1024];
    int t = threadIdx.x;
    int v = (t < nb) ? bsum[t] : 0;
    s[t] = v;
    __syncthreads();
    for (int off = 1; off < 1024; off <<= 1) {
        int add = (t >= off) ? s[t - off] : 0;
        __syncthreads();
        s[t] += add;
        __syncthreads();
    }
    __syncthreads();
    int i = blockIdx.x * 1024 + t;
    if (i < n) data[i] += s[i >> 10] - ((i >> 10) < nb ? bsum[i >> 10] : 0);
}

// ---------------- scan3bf: same for M2, also emits offsets ---------------
__global__ void scan3bf_kernel(int* __restrict__ data, const int* __restrict__ bsum,
                               int nb, int* __restrict__ offsets) {
    __shared__ int s[1024];
    int t = threadIdx.x;
    int v = (t < nb) ? bsum[t] : 0;
    s[t] = v;
    __syncthreads();
    for (int off = 1; off < 1024; off <<= 1) {
        int add = (t >= off) ? s[t - off] : 0;
        __syncthreads();
        s[t] += add;
        __syncthreads();
    }
    __syncthreads();
    int i = blockIdx.x * 1024 + t;
    if (i >= N2) return;
    int blk = i >> 10;
    int vv = data[i] + s[blk] - (blk < nb ? bsum[blk] : 0);
    data[i] = vv;
    if (i % WPB == 0) {
        int nbidx = i / WPB;                  // = bucket*512 + bin
        if (nbidx <= NN) offsets[nbidx] = vv;
    }
}

// ---------------- pass 1 histogram (bin = src>>9), 1024 threads ----------
__global__ void hist1_kernel(const int* __restrict__ ei, int* __restrict__ counts1) {
    __shared__ int h[NBINS1];
    int t = threadIdx.x;
    if (t < NBINS1) h[t] = 0;
    __syncthreads();
    int base = blockIdx.x * EPB;
    for (int j = t; j < EPB; j += 1024) {
        int e = base + j;
        if (e < NE) atomicAdd(&h[ei[e] >> 9], 1);
    }
    __syncthreads();
    if (t < NBINS1) counts1[t * NBLKS1 + blockIdx.x] = h[t];   // bin-major
}

// ---------------- pass 1 scatter: key packed into pk.x bits 17+ ----------
__global__ void scatter1_kernel(const int* __restrict__ ei,
                                const float* __restrict__ ea,
                                const int* __restrict__ counts1s,
                                int2* __restrict__ pk1) {
    __shared__ int cur[NBINS1];
    int t = threadIdx.x;
    if (t < NBINS1) cur[t] = counts1s[t * NBLKS1 + blockIdx.x];
    __syncthreads();
    int base = blockIdx.x * EPB;
    for (int j = t; j < EPB; j += 1024) {
        int e = base + j;
        if (e >= NE) break;
        int src = ei[e];
        int pos = atomicAdd(&cur[src >> 9], 1);
        int2 pk;
        pk.x = ei[NE + e] | ((src & 511) << 17);
        pk.y = __float_as_int(ea[e]);
        pk1[pos] = pk;
    }
}

// ---------------- pass 2 histogram (key from pk1.x bits 17+) -------------
__global__ void hist2_kernel(const int2* __restrict__ pk1,
                             const int* __restrict__ counts1s,
                             int* __restrict__ M2) {
    __shared__ int h[512];
    int t = threadIdx.x;
    h[t] = 0; h[t + 256] = 0;
    __syncthreads();
    int b = blockIdx.x / WPB, w = blockIdx.x % WPB;
    int bstart = counts1s[b * NBLKS1];
    int bend   = counts1s[(b + 1) * NBLKS1];
    int start = bstart + w * WIN;
    int end = (start + WIN < bend) ? (start + WIN) : bend;
    for (int i = start + t; i < end; i += 256)
        atomicAdd(&h[(pk1[i].x >> 17) & 511], 1);
    __syncthreads();
    M2[((b * 512) + t) * WPB + w]       = h[t];
    M2[((b * 512) + t + 256) * WPB + w] = h[t + 256];
}

// ---------------- pass 2 scatter (final positions; strip key) ------------
__global__ void scatter2_kernel(const int2* __restrict__ pk1,
                                const int* __restrict__ counts1s,
                                const int* __restrict__ M2s,
                                int2* __restrict__ csr_pk) {
    __shared__ int cur[512];
    int t = threadIdx.x;
    int b = blockIdx.x / WPB, w = blockIdx.x % WPB;
    cur[t]       = M2s[((b * 512) + t) * WPB + w];
    cur[t + 256] = M2s[((b * 512) + t + 256) * WPB + w];
    __syncthreads();
    int bstart = counts1s[b * NBLKS1];
    int bend   = counts1s[(b + 1) * NBLKS1];
    int start = bstart + w * WIN;
    int end = (start + WIN < bend) ? (start + WIN) : bend;
    for (int i = start + t; i < end; i += 256) {
        int2 pk = pk1[i];
        int pos = atomicAdd(&cur[(pk.x >> 17) & 511], 1);
        pk.x &= KMASK;
        csr_pk[pos] = pk;
    }
}

// ---------------- fused: MLP table (blocks 0..15) + xpack2 (rest) --------
__global__ void prep_kernel(const float* __restrict__ W1,
                            const float* __restrict__ b1,
                            const float* __restrict__ W2,
                            const float* __restrict__ b2,
                            const float* __restrict__ x,
                            unsigned short* __restrict__ tab,
                            int* __restrict__ xbf2) {
    const int TBLK = (TBINS + 255) / 256;      // 16 blocks for table
    if (blockIdx.x < TBLK) {
        int i = blockIdx.x * 256 + threadIdx.x;
        if (i >= TBINS) return;
        float m0[EOUTD], m1[EOUTD];
        float d0 = (float)i * (10.0f / (float)TBINS);
        float d1 = (float)(i + 1) * (10.0f / (float)TBINS);
        #pragma unroll
        for (int j = 0; j < EOUTD; ++j) { m0[j] = b2[j]; m1[j] = b2[j]; }
        for (int k = 0; k < EHD; ++k) {
            float h0 = fmaxf(fmaf(d0, W1[k], b1[k]), 0.0f);
            float h1 = fmaxf(fmaf(d1, W1[k], b1[k]), 0.0f);
            #pragma unroll
            for (int j = 0; j < EOUTD; ++j) {
                m0[j] = fmaf(h0, W2[k * EOUTD + j], m0[j]);
                m1[j] = fmaf(h1, W2[k * EOUTD + j], m1[j]);
            }
        }
        unsigned short* row = tab + (size_t)i * 32;
        #pragma unroll
        for (int j = 0; j < EOUTD; ++j) {
            unsigned int uv = __float_as_uint(m0[j]);
            unsigned int ud = __float_as_uint(m1[j] - m0[j]);
            uv = (uv + 0x7fffu + ((uv >> 16) & 1u)) >> 16;
            ud = (ud + 0x7fffu + ((ud >> 16) & 1u)) >> 16;
            row[2 * j]     = (unsigned short)uv;
            row[2 * j + 1] = (unsigned short)ud;
        }
        #pragma unroll
        for (int j = 20; j < 32; ++j) row[j] = 0;
    } else {
        int t = (blockIdx.x - TBLK) * 256 + threadIdx.x;
        if (t >= NN * 16) return;
        int node = t >> 4, k = t & 15;
        int v = 0;
        if (k < 10) {
            unsigned int u0 = __float_as_uint(x[(size_t)node * 2 * HD + k]);
            unsigned int u1 = __float_as_uint(x[(size_t)node * 2 * HD + k + 10]);
            u0 = (u0 + 0x7fffu + ((u0 >> 16) & 1u)) >> 16;   // RNE bf16
            u1 = (u1 + 0x7fffu + ((u1 >> 16) & 1u)) >> 16;
            v = (int)(u0 | (u1 << 16));
        }
        xbf2[t] = v;
    }
}

// ---------------- node-owner kernel: 10 lanes/node, 2 features/lane -------
__launch_bounds__(256)
__global__ void node_kernel(const int* __restrict__ offsets,
                            const int2* __restrict__ csr_pk,
                            const float* __restrict__ x,
                            const int* __restrict__ xbf2,
                            const unsigned short* __restrict__ tab,
                            const float* __restrict__ pa,
                            const float* __restrict__ pb,
                            const float* __restrict__ g1,
                            const float* __restrict__ g2,
                            const float* __restrict__ bias,
                            float* __restrict__ out) {
    int tid  = threadIdx.x;
    int wave = tid >> 6;
    int lane = tid & 63;
    int sub  = lane / 10;                  // 0..5 active, 6 = idle lanes
    int fk   = lane - sub * 10;            // feature pair id 0..9
    int node = blockIdx.x * 24 + wave * 6 + sub;
    bool active = (sub < 6) && (node < NN);

    float a = pa[0], bb = pb[0];
    float oma = 1.0f - a;

    int off0 = 0, deg = 0;
    float xs_lo = 0.0f, xs_hi = 0.0f, axs_lo = 0.0f, axs_hi = 0.0f;
    if (active) {
        off0 = offsets[node];
        deg  = offsets[node + 1] - off0;
        xs_lo = x[(size_t)node * 2 * HD + fk];
        xs_hi = x[(size_t)node * 2 * HD + fk + 10];
        axs_lo = a * xs_lo;
        axs_hi = a * xs_hi;
    }

    float S0a = 0.0f, S1a = 0.0f, Sra = 0.0f;   // feature fk (one-hot)
    float S0b = 0.0f, S1b = 0.0f, Srb = 0.0f;   // feature fk+10 (table)

    auto process = [&](int dst, int db) {
        float d = __int_as_float(db);
        int idx = (int)d; if (idx > 9) idx = 9;
        float u = d * ((float)TBINS / 10.0f);
        int ti = (int)u; if (ti > TBINS - 1) ti = TBINS - 1;
        float fr = u - (float)ti;
        unsigned int xw = (unsigned int)xbf2[(((size_t)(unsigned int)dst) << 4) + fk];
        unsigned int tv = *(const unsigned int*)(tab + (((size_t)ti) << 5) + fk * 2);
        float xd_lo = __uint_as_float(xw << 16);
        float xd_hi = __uint_as_float(xw & 0xffff0000u);
        float t0 = fmaf(-oma, xd_lo, axs_lo);
        float t1 = fmaf(-oma, xd_hi, axs_hi);
        float r0 = (t0 != 0.0f)
            ? __builtin_amdgcn_exp2f(bb * __builtin_amdgcn_logf(fabsf(t0))) : 0.0f;
        float r1 = (t1 != 0.0f)
            ? __builtin_amdgcn_exp2f(bb * __builtin_amdgcn_logf(fabsf(t1))) : 0.0f;
        Sra += r0; Srb += r1;
        float c0 = (fk == idx) ? 1.0f : 0.0f;
        float val = __uint_as_float(tv << 16);
        float del = __uint_as_float(tv & 0xffff0000u);
        float c1 = fmaxf(fmaf(fr, del, val), 0.0f);
        S0a += c0; S1a = fmaf(r0, c0, S1a);
        S0b += c1; S1b = fmaf(r1, c1, S1b);
    };

    for (int base = 0; base < deg; base += 10) {
        int nchunk = deg - base; if (nchunk > 10) nchunk = 10;
        // clamped (branch-free) coalesced preload of this chunk's (dst,d)
        int idxc = off0 + base + ((fk < nchunk) ? fk : (nchunk - 1));
        int2 pk = csr_pk[idxc];
        int dstv = pk.x, dbits = pk.y;
        int jj = 0;
        for (; jj + 1 < nchunk; jj += 2) {
            int dA = __shfl(dstv, sub * 10 + jj, 64);
            int bA = __shfl(dbits, sub * 10 + jj, 64);
            int dB = __shfl(dstv, sub * 10 + jj + 1, 64);
            int bB = __shfl(dbits, sub * 10 + jj + 1, 64);
            process(dA, bA);
            process(dB, bB);
        }
        if (jj < nchunk) {
            int dA = __shfl(dstv, sub * 10 + jj, 64);
            int bA = __shfl(dbits, sub * 10 + jj, 64);
            process(dA, bA);
        }
    }

    float sf_lo = (S0a != 0.0f) ? (S1a / S0a) : (0.01f * Sra);
    float sf_hi = (S0b != 0.0f) ? (S1b / S0b) : (0.01f * Srb);

    if (active) {
        // epilogue: lane fk computes output rows fk and fk+10
        float acc0 = bias[fk];
        float acc1 = bias[fk + 10];
        const float* g1r0 = g1 + fk * HD;
        const float* g1r1 = g1 + (fk + 10) * HD;
        const float* g2r0 = g2 + fk * HD;
        const float* g2r1 = g2 + (fk + 10) * HD;
        #pragma unroll
        for (int j = 0; j < 10; ++j) {
            int sl = sub * 10 + j;
            float xj  = __shfl(xs_lo, sl, 64);
            float xj1 = __shfl(xs_hi, sl, 64);
            float sj  = __shfl(sf_lo, sl, 64);
            float sj1 = __shfl(sf_hi, sl, 64);
            acc0 = fmaf(xj, g1r0[j], acc0);  acc0 = fmaf(xj1, g1r0[j + 10], acc0);
            acc0 = fmaf(sj, g2r0[j], acc0);  acc0 = fmaf(sj1, g2r0[j + 10], acc0);
            acc1 = fmaf(xj, g1r1[j], acc1);  acc1 = fmaf(xj1, g1r1[j + 10], acc1);
            acc1 = fmaf(sj, g2r1[j], acc1);  acc1 = fmaf(sj1, g2r1[j + 10], acc1);
        }
        float* op = out + (size_t)node * 2 * HD;
        op[fk]          = fmaxf(acc0, 0.0f);
        op[fk + 10]     = fmaxf(acc1, 0.0f);
        op[HD + fk]     = sf_lo;
        op[HD + fk + 10] = sf_hi;
    }
}

extern "C" void kernel_launch(void* const* d_in, const int* in_sizes, int n_in,
                              void* d_out, int out_size, void* d_ws, size_t ws_size,
                              hipStream_t stream) {
    const float* x    = (const float*)d_in[0];
    const int*   ei   = (const int*)d_in[1];
    const float* ea   = (const float*)d_in[2];
    const float* pa   = (const float*)d_in[3];
    const float* pb   = (const float*)d_in[4];
    const float* g1   = (const float*)d_in[5];
    const float* g2   = (const float*)d_in[6];
    const float* bias = (const float*)d_in[7];
    const float* W1   = (const float*)d_in[8];
    const float* b1   = (const float*)d_in[9];
    const float* W2   = (const float*)d_in[10];
    const float* b2   = (const float*)d_in[11];
    float* out = (float*)d_out;

    // workspace layout (all segments 128B-aligned)
    char* ws = (char*)d_ws;
    int*   counts1 = (int*)ws;     ws += ((size_t)N1 * 4 + 127) / 128 * 128;
    int*   bsum1   = (int*)ws;     ws += (1024 * 4 + 127) / 128 * 128;
    int*   M2      = (int*)ws;     ws += ((size_t)N2 * 4 + 127) / 128 * 128;
    int*   bsum2   = (int*)ws;     ws += (1024 * 4 + 127) / 128 * 128;
    int*   offsets = (int*)ws;     ws += ((size_t)(NN + 1) * 4 + 127) / 128 * 128;
    int2*  pk1     = (int2*)ws;    ws += (size_t)NE * 8;
    int2*  csr_pk  = (int2*)ws;    ws += (size_t)NE * 8;
    unsigned short* tab = (unsigned short*)ws;   ws += ((size_t)TBINS * 32 * 2 + 127) / 128 * 128;
    int*   xbf2    = (int*)ws;     ws += ((size_t)NN * 16 * 4 + 127) / 128 * 128;

    const int TBLK = (TBINS + 255) / 256;
    prep_kernel<<<TBLK + (NN * 16 + 255) / 256, 256, 0, stream>>>(W1, b1, W2, b2, x,
                                                                  tab, xbf2);

    // pass 1: group by bucket (src>>9)
    const int nb1 = (N1 + 1023) / 1024;
    hist1_kernel<<<NBLKS1, 1024, 0, stream>>>(ei, counts1);
    scan1_kernel<<<nb1, 1024, 0, stream>>>(counts1, bsum1, N1);
    scan3f_kernel<<<nb1, 1024, 0, stream>>>(counts1, bsum1, nb1, N1);
    scatter1_kernel<<<NBLKS1, 1024, 0, stream>>>(ei, ea, counts1, pk1);

    // pass 2: within bucket, bin = src & 511 (== exact node)
    const int nb2 = (N2 + 1023) / 1024;
    hist2_kernel<<<NWIN, 256, 0, stream>>>(pk1, counts1, M2);
    scan1_kernel<<<nb2, 1024, 0, stream>>>(M2, bsum2, N2);
    scan3bf_kernel<<<nb2, 1024, 0, stream>>>(M2, bsum2, nb2, offsets);
    scatter2_kernel<<<NWIN, 256, 0, stream>>>(pk1, counts1, M2, csr_pk);

    node_kernel<<<(NN + 23) / 24, 256, 0, stream>>>(offsets, csr_pk, x, xbf2, tab,
                                                    pa, pb, g1, g2, bias, out);
}